// Round 4
// baseline (268.641 us; speedup 1.0000x reference)
//
#include <hip/hip_runtime.h>
#include <cstdint>
#include <cstddef>

#define B_N   16
#define G_N   128
#define FD_N  8192
#define KSPLIT 16
#define KC    512        // FD_N / KSPLIT
#define BK2   32
#define NITER 16         // KC / BK2

typedef unsigned short u16;
typedef u16  u16x4 __attribute__((ext_vector_type(4)));
typedef u16  u16x8 __attribute__((ext_vector_type(8)));
typedef __bf16 bf16x8 __attribute__((ext_vector_type(8)));
typedef float f32x16 __attribute__((ext_vector_type(16)));

// ---- ws layout (float offsets). Everything written before read; NO zero-init needed.
#define QSUM_P   0        // [kch][b][row] 16*16*128
#define QSSQ_P   32768
#define KSUM_P   65536
#define KSSQ_P   98304
#define NSSQ_P   131072
#define SM_ROW   163840   // [b][row]
#define CE_ROW   165888
#define S_OFF    167936   // [b][128][128] fp32 normalized S
#define CONTRIB  430080   // [128]
#define PART_OFF_F 430208 // u16 region: [512 blk][128][128] bf16 partials (16.8 MB)

__device__ __forceinline__ u16 f2bf(float f) {
    uint32_t u = __float_as_uint(f);
    u += 0x7FFFu + ((u >> 16) & 1u);      // RNE
    return (u16)(u >> 16);
}

// Drain ONLY LDS ops at the barrier — global prefetch loads stay in flight.
#define LDS_BARRIER() asm volatile("s_waitcnt lgkmcnt(0)\n\ts_barrier" ::: "memory")

// ================= K1: bf16 GEMM 128x128 tile (A=q, B=k|n), depth-2 prefetch, BK=32 ===========
// grid = 16*2*16 = 512 blocks x 512 thr (2 blocks/CU). Partials + per-chunk stats, no atomics.
__global__ __launch_bounds__(512, 4)
void k_gemm(const float* __restrict__ q, const float* __restrict__ kM,
            const float* __restrict__ nM, float* __restrict__ ws)
{
    __shared__ __align__(16) u16 sA[G_N * BK2];   // 8 KB
    __shared__ __align__(16) u16 sB[G_N * BK2];   // 8 KB

    const int tid = threadIdx.x;
    const int blk = blockIdx.x;
    const int b    = blk >> 5;
    const int rem  = blk & 31;
    const int half = rem >> 4;        // 0: B=k, 1: B=n
    const int kch  = rem & 15;

    const int r0 = tid >> 3;          // 0..63 (rows r0, r0+64)
    const int c8 = tid & 7;           // 8 threads/row * 4 floats = 32 cols

    const size_t mat_off = (size_t)b * (G_N * FD_N) + (size_t)kch * KC + (size_t)(c8 * 4);
    const float* Ap = q + mat_off;
    const float* Bp = (half ? nM : kM) + mat_off;

    float4 la[2][2], lb[2][2];
    float aS[2] = {0,0}, aQ[2] = {0,0}, bS[2] = {0,0}, bQ[2] = {0,0};

    // prologue: stage 0 = tile 0, stage 1 = tile 1 (issue order = consumption order)
    #pragma unroll
    for (int st = 0; st < 2; ++st) {
        const float* A2 = Ap + st * BK2;
        const float* B2 = Bp + st * BK2;
        #pragma unroll
        for (int i = 0; i < 2; ++i) {
            la[st][i] = *(const float4*)(A2 + (size_t)(r0 + 64*i) * FD_N);
            lb[st][i] = *(const float4*)(B2 + (size_t)(r0 + 64*i) * FD_N);
        }
    }

    const int lane  = tid & 63;
    const int wv    = tid >> 6;       // 8 waves
    const int wm    = wv >> 2;        // 0..1 -> 64-row block
    const int wn    = wv & 3;         // 0..3 -> 32-col block
    const int khalf = lane >> 5;
    const int lrow  = lane & 31;
    const int rA0 = wm*64 + lrow;
    const int rB0 = wn*32 + lrow;

    f32x16 acc[2];
    #pragma unroll
    for (int mb = 0; mb < 2; ++mb)
      #pragma unroll
      for (int e = 0; e < 16; ++e) acc[mb][e] = 0.f;

    for (int kb = 0; kb < NITER; ++kb) {
        const int st = kb & 1;
        LDS_BARRIER();     // prior MFMA ds_reads done; vm loads keep flowing
        #pragma unroll
        for (int i = 0; i < 2; ++i) {
            int row = r0 + 64*i;
            int wof = row*BK2 + (((c8>>1) ^ (row&3))<<3) + ((c8&1)<<2);
            float4 v = la[st][i];
            aS[i] += v.x + v.y + v.z + v.w;
            aQ[i] += v.x*v.x + v.y*v.y + v.z*v.z + v.w*v.w;
            u16x4 h; h[0]=f2bf(v.x); h[1]=f2bf(v.y); h[2]=f2bf(v.z); h[3]=f2bf(v.w);
            *(u16x4*)(sA + wof) = h;
            v = lb[st][i];
            bS[i] += v.x + v.y + v.z + v.w;
            bQ[i] += v.x*v.x + v.y*v.y + v.z*v.z + v.w*v.w;
            u16x4 h2; h2[0]=f2bf(v.x); h2[1]=f2bf(v.y); h2[2]=f2bf(v.z); h2[3]=f2bf(v.w);
            *(u16x4*)(sB + wof) = h2;
        }
        LDS_BARRIER();
        if (kb + 2 < NITER) {          // refill this stage with tile kb+2
            const float* A2 = Ap + (kb+2) * BK2;
            const float* B2 = Bp + (kb+2) * BK2;
            #pragma unroll
            for (int i = 0; i < 2; ++i) {
                la[st][i] = *(const float4*)(A2 + (size_t)(r0 + 64*i) * FD_N);
                lb[st][i] = *(const float4*)(B2 + (size_t)(r0 + 64*i) * FD_N);
            }
        }
        #pragma unroll
        for (int s = 0; s < 2; ++s) {
            int chunk = s*2 + khalf;
            bf16x8 af[2], bfv;
            #pragma unroll
            for (int mb = 0; mb < 2; ++mb) {
                int row = rA0 + mb*32;
                u16x8 raw = *(const u16x8*)(sA + row*BK2 + ((chunk ^ (row&3))<<3));
                af[mb] = __builtin_bit_cast(bf16x8, raw);
            }
            u16x8 rawb = *(const u16x8*)(sB + rB0*BK2 + ((chunk ^ (rB0&3))<<3));
            bfv = __builtin_bit_cast(bf16x8, rawb);
            acc[0] = __builtin_amdgcn_mfma_f32_32x32x16_bf16(af[0], bfv, acc[0], 0, 0, 0);
            acc[1] = __builtin_amdgcn_mfma_f32_32x32x16_bf16(af[1], bfv, acc[1], 0, 0, 0);
        }
    }

    // bf16 partial C: C/D layout col=lane&31, row=(reg&3)+8*(reg>>2)+4*(lane>>5)
    u16* part = (u16*)(ws + PART_OFF_F) + ((size_t)blk << 14);
    #pragma unroll
    for (int mb = 0; mb < 2; ++mb) {
        int col = wn*32 + lrow;
        int rbase = wm*64 + mb*32 + 4*khalf;
        #pragma unroll
        for (int reg = 0; reg < 16; ++reg) {
            int row = rbase + (reg & 3) + 8*(reg >> 2);
            part[row*G_N + col] = f2bf(acc[mb][reg]);
        }
    }

    // per-chunk row stats, non-atomic (reduce over the 8 lanes sharing a row)
    #pragma unroll
    for (int i = 0; i < 2; ++i) {
        float sa = aS[i], qa = aQ[i], sb = bS[i], qb = bQ[i];
        #pragma unroll
        for (int m = 4; m >= 1; m >>= 1) {
            sa += __shfl_xor(sa, m, 64); qa += __shfl_xor(qa, m, 64);
            sb += __shfl_xor(sb, m, 64); qb += __shfl_xor(qb, m, 64);
        }
        if (c8 == 0) {
            int o = kch*2048 + b*G_N + (r0 + 64*i);
            if (half == 0) {
                ws[QSUM_P + o] = sa; ws[QSSQ_P + o] = qa;
                ws[KSUM_P + o] = sb; ws[KSSQ_P + o] = qb;
            } else {
                ws[NSSQ_P + o] = qb;
            }
        }
    }
}

// ================= K2: reduce chunks + normalize + write S / sm-row / CE-expsum-row ==========
// grid = 16b * 2half * 8rowgroups = 256 blocks x 256 thr. thread = (row in 16, 8-col group).
__global__ __launch_bounds__(256)
void k_red2(float* __restrict__ ws)
{
    const int blk  = blockIdx.x;
    const int b    = blk >> 4;
    const int half = (blk >> 3) & 1;
    const int rg   = blk & 7;
    const int t    = threadIdx.x;
    const int lr   = t >> 4;            // 0..15
    const int i    = rg*16 + lr;
    const int c8   = t & 15;            // 8 cols each
    __shared__ float nrm[128];          // 1/||k_j|| or 1/||n_j||
    __shared__ float invq_s[16];

    if (t < 128) {
        float ss = 0.f;
        const float* p = ws + (half ? NSSQ_P : KSSQ_P) + b*G_N + t;
        #pragma unroll
        for (int kc2 = 0; kc2 < KSPLIT; ++kc2) ss += p[kc2*2048];
        nrm[t] = 1.f / fmaxf(sqrtf(ss), 1e-12f);
    } else if (t < 144) {
        float ss = 0.f;
        const float* p = ws + QSSQ_P + b*G_N + rg*16 + (t - 128);
        #pragma unroll
        for (int kc2 = 0; kc2 < KSPLIT; ++kc2) ss += p[kc2*2048];
        invq_s[t-128] = 1.f / fmaxf(sqrtf(ss), 1e-12f);
    }
    __syncthreads();

    const u16* part = (const u16*)(ws + PART_OFF_F);
    float s[8] = {0,0,0,0,0,0,0,0};
    #pragma unroll
    for (int kc2 = 0; kc2 < KSPLIT; ++kc2) {
        size_t idx = ((size_t)(b*32 + half*16 + kc2) << 14) + i*G_N + c8*8;
        u16x8 h = *(const u16x8*)(part + idx);
        #pragma unroll
        for (int e = 0; e < 8; ++e)
            s[e] += __uint_as_float(((uint32_t)h[e]) << 16);
    }
    const float iq = invq_s[lr];
    if (half == 0) {
        float smacc = 0.f;
        float S8[8];
        #pragma unroll
        for (int e = 0; e < 8; ++e) {
            int j = c8*8 + e;
            S8[e] = s[e] * iq * nrm[j];
            float d = S8[e] - (j == i ? 1.f : 0.f);
            smacc += d*d;
        }
        float* Sp = ws + S_OFF + (size_t)b*16384 + i*G_N + c8*8;
        float4 w0 = {S8[0],S8[1],S8[2],S8[3]};
        float4 w1 = {S8[4],S8[5],S8[6],S8[7]};
        *(float4*)Sp = w0; *(float4*)(Sp+4) = w1;
        #pragma unroll
        for (int m = 8; m >= 1; m >>= 1) smacc += __shfl_xor(smacc, m, 64);
        if (c8 == 0) ws[SM_ROW + b*G_N + i] = smacc;
    } else {
        float eacc = 0.f;
        #pragma unroll
        for (int e = 0; e < 8; ++e)
            eacc += __expf(5.f * s[e] * iq * nrm[c8*8+e]);
        #pragma unroll
        for (int m = 8; m >= 1; m >>= 1) eacc += __shfl_xor(eacc, m, 64);
        if (c8 == 0) ws[CE_ROW + b*G_N + i] = eacc;
    }
}

// ================= K3: tri/cyc/ce + weighted per-block contrib =================
// grid = 16b * 8rowgroups = 128 blocks x 256 thr.
__global__ __launch_bounds__(256)
void k_epi(float* __restrict__ ws)
{
    const int blk = blockIdx.x;
    const int b   = blk >> 3;
    const int i0  = (blk & 7) * 16;
    const int t   = threadIdx.x;
    __shared__ float sqv[128], skv[128], ddq[128], ddk[128];
    __shared__ float rbuf[4];
    const float c0 = (float)FD_N * 1e-6f * 1e-6f;

    const float* S = ws + S_OFF + (size_t)b * 16384;
    if (t < 128) {
        float qs=0, qq=0, ks=0, kq=0;
        #pragma unroll
        for (int kc2 = 0; kc2 < KSPLIT; ++kc2) {
            int o = kc2*2048 + b*G_N + t;
            qs += ws[QSUM_P + o]; qq += ws[QSSQ_P + o];
            ks += ws[KSUM_P + o]; kq += ws[KSSQ_P + o];
        }
        float iq = 1.f/fmaxf(sqrtf(qq),1e-12f);
        float ik = 1.f/fmaxf(sqrtf(kq),1e-12f);
        float sq = qs*iq, sk = ks*ik;
        sqv[t]=sq; skv[t]=sk;
        float Stt = S[t*G_N + t];
        ddq[t] = sqrtf(fmaxf(2.f - 2.f*Stt + 2e-6f*(sq-sk) + c0, 0.f));
        ddk[t] = sqrtf(fmaxf(2.f - 2.f*Stt + 2e-6f*(sk-sq) + c0, 0.f));
    }
    __syncthreads();

    float tri=0.f, cyc=0.f, ce=0.f, sm=0.f;
    #pragma unroll
    for (int p = 0; p < 8; ++p) {
        int idx = p*256 + t;
        int i = i0 + (idx >> 7), j = idx & 127;
        if (i != j) {
            float S_ij = S[i*G_N + j];
            float dqk = sqrtf(fmaxf(2.f - 2.f*S_ij + 2e-6f*(sqv[i]-skv[j]) + c0, 0.f));
            tri += fmaxf(ddq[i] - dqk + 1.f, 0.f);
            float dkq = sqrtf(fmaxf(2.f - 2.f*S_ij + 2e-6f*(skv[j]-sqv[i]) + c0, 0.f));
            tri += fmaxf(ddk[j] - dkq + 1.f, 0.f);
            cyc += fabsf(S_ij - S[j*G_N + i]);
        }
    }
    if (t < 16) {
        int r = i0 + t;
        float lp = 5.f * S[r*G_N + r];
        ce = __logf(ws[CE_ROW + b*G_N + r] + __expf(lp)) - lp;
        sm = ws[SM_ROW + b*G_N + r];
    }
    float contrib = sm * (1.f/16384.f) + cyc * (1.f/16256.f) + ce * (1.f/16384.f)
                  + (float)(B_N - b) * tri * (1.f/32512.f);
    #pragma unroll
    for (int m = 32; m >= 1; m >>= 1) contrib += __shfl_xor(contrib, m, 64);
    if ((t & 63) == 0) rbuf[t >> 6] = contrib;
    __syncthreads();
    if (t == 0) ws[CONTRIB + blk] = rbuf[0] + rbuf[1] + rbuf[2] + rbuf[3];
}

// ================= K4: sum 128 contribs -> out (plain store, no memset needed) ============
__global__ void k_fin(const float* __restrict__ ws, float* __restrict__ out)
{
    __shared__ float r2[2];
    int t = threadIdx.x;            // 128
    float v = ws[CONTRIB + t];
    #pragma unroll
    for (int m = 32; m >= 1; m >>= 1) v += __shfl_xor(v, m, 64);
    if ((t & 63) == 0) r2[t >> 6] = v;
    __syncthreads();
    if (t == 0) out[0] = r2[0] + r2[1];
}

extern "C" void kernel_launch(void* const* d_in, const int* in_sizes, int n_in,
                              void* d_out, int out_size, void* d_ws, size_t ws_size,
                              hipStream_t stream)
{
    const float* q  = (const float*)d_in[0];
    const float* kM = (const float*)d_in[1];
    const float* nM = (const float*)d_in[2];
    float* ws  = (float*)d_ws;
    float* out = (float*)d_out;

    k_gemm<<<B_N * 2 * KSPLIT, 512, 0, stream>>>(q, kM, nM, ws);
    k_red2<<<256, 256, 0, stream>>>(ws);
    k_epi<<<128, 256, 0, stream>>>(ws);
    k_fin<<<1, 128, 0, stream>>>(ws, out);
}

// Round 5
// 218.553 us; speedup vs baseline: 1.2292x; 1.2292x over previous
//
#include <hip/hip_runtime.h>
#include <cstdint>
#include <cstddef>

#define B_N   16
#define G_N   128
#define FD_N  8192
#define KSPLIT 16
#define KC    512        // FD_N / KSPLIT
#define BK2   32
#define NITER 16         // KC / BK2

typedef unsigned short u16;
typedef u16  u16x4 __attribute__((ext_vector_type(4)));
typedef u16  u16x8 __attribute__((ext_vector_type(8)));
typedef __bf16 bf16x8 __attribute__((ext_vector_type(8)));
typedef float f32x16 __attribute__((ext_vector_type(16)));

// ---- ws layout (float offsets). Everything written before read; NO zero-init needed.
#define QSUM_P   0        // [kch][b][row] 16*16*128
#define QSSQ_P   32768
#define KSUM_P   65536
#define KSSQ_P   98304
#define NSSQ_P   131072
#define SM_ROW   163840   // [b][row]
#define CE_ROW   165888
#define S_OFF    167936   // [b][128][128] fp32 normalized S
#define PART_OFF_F 430080 // u16 region: [512 blk][128][128] bf16 partials (16.8 MB)

__device__ __forceinline__ u16 f2bf(float f) {
    uint32_t u = __float_as_uint(f);
    u += 0x7FFFu + ((u >> 16) & 1u);      // RNE
    return (u16)(u >> 16);
}

// Drain ONLY LDS ops at the barrier — global prefetch loads stay in flight.
#define LDS_BARRIER() asm volatile("s_waitcnt lgkmcnt(0)\n\ts_barrier" ::: "memory")

// ================= K1: bf16 GEMM 128x128 tile (A=q, B=k|n), depth-2 prefetch, BK=32 ===========
// grid = 16*2*16 = 512 blocks x 512 thr (2 blocks/CU).
// Stage registers are SEPARATE NAMED arrays (a0/b0, a1/b1) with compile-time indices only —
// dynamic indexing (r4's la[st][i]) demotes arrays to scratch => 240 MB spill traffic.
__global__ __launch_bounds__(512, 4)
void k_gemm(const float* __restrict__ q, const float* __restrict__ kM,
            const float* __restrict__ nM, float* __restrict__ ws)
{
    __shared__ __align__(16) u16 sA[G_N * BK2];   // 8 KB
    __shared__ __align__(16) u16 sB[G_N * BK2];   // 8 KB

    const int tid = threadIdx.x;
    const int blk = blockIdx.x;
    const int b    = blk >> 5;
    const int rem  = blk & 31;
    const int half = rem >> 4;        // 0: B=k, 1: B=n
    const int kch  = rem & 15;

    const int r0 = tid >> 3;          // 0..63 (rows r0, r0+64)
    const int c8 = tid & 7;           // 8 threads/row * 4 floats = 32 cols

    const size_t mat_off = (size_t)b * (G_N * FD_N) + (size_t)kch * KC + (size_t)(c8 * 4);
    const float* Ap = q + mat_off;
    const float* Bp = (half ? nM : kM) + mat_off;

    float4 a0[2], b0[2], a1[2], b1[2];
    float aS[2] = {0,0}, aQ[2] = {0,0}, bS[2] = {0,0}, bQ[2] = {0,0};

    // prologue: stage0 = tile 0, stage1 = tile 1
    #pragma unroll
    for (int i = 0; i < 2; ++i) {
        size_t ro = (size_t)(r0 + 64*i) * FD_N;
        a0[i] = *(const float4*)(Ap + ro);
        b0[i] = *(const float4*)(Bp + ro);
    }
    #pragma unroll
    for (int i = 0; i < 2; ++i) {
        size_t ro = (size_t)(r0 + 64*i) * FD_N + BK2;
        a1[i] = *(const float4*)(Ap + ro);
        b1[i] = *(const float4*)(Bp + ro);
    }

    const int lane  = tid & 63;
    const int wv    = tid >> 6;       // 8 waves
    const int wm    = wv >> 2;        // 0..1 -> 64-row block
    const int wn    = wv & 3;         // 0..3 -> 32-col block
    const int khalf = lane >> 5;
    const int lrow  = lane & 31;
    const int rA0 = wm*64 + lrow;
    const int rB0 = wn*32 + lrow;

    // precompute swizzled LDS offsets (u16 units)
    int wof[2];
    #pragma unroll
    for (int i = 0; i < 2; ++i) {
        int row = r0 + 64*i;
        wof[i] = row*BK2 + 8*((c8>>1) ^ ((row>>1)&3)) + 4*(c8&1);
    }

    f32x16 acc[2];
    #pragma unroll
    for (int mb = 0; mb < 2; ++mb)
      #pragma unroll
      for (int e = 0; e < 16; ++e) acc[mb][e] = 0.f;

#define STORE_STAGE(AR, BR)                                                   \
    {                                                                         \
        _Pragma("unroll")                                                     \
        for (int i = 0; i < 2; ++i) {                                         \
            float4 v = AR[i];                                                 \
            aS[i] += v.x + v.y + v.z + v.w;                                   \
            aQ[i] += v.x*v.x + v.y*v.y + v.z*v.z + v.w*v.w;                   \
            u16x4 h; h[0]=f2bf(v.x); h[1]=f2bf(v.y); h[2]=f2bf(v.z); h[3]=f2bf(v.w); \
            *(u16x4*)(sA + wof[i]) = h;                                       \
            v = BR[i];                                                        \
            bS[i] += v.x + v.y + v.z + v.w;                                   \
            bQ[i] += v.x*v.x + v.y*v.y + v.z*v.z + v.w*v.w;                   \
            u16x4 h2; h2[0]=f2bf(v.x); h2[1]=f2bf(v.y); h2[2]=f2bf(v.z); h2[3]=f2bf(v.w); \
            *(u16x4*)(sB + wof[i]) = h2;                                      \
        }                                                                     \
    }

#define REFILL(AR, BR, KOFF)                                                  \
    {                                                                         \
        _Pragma("unroll")                                                     \
        for (int i = 0; i < 2; ++i) {                                         \
            size_t ro = (size_t)(r0 + 64*i) * FD_N + (KOFF);                  \
            AR[i] = *(const float4*)(Ap + ro);                                \
            BR[i] = *(const float4*)(Bp + ro);                                \
        }                                                                     \
    }

#define MFMA_PHASE()                                                          \
    {                                                                         \
        _Pragma("unroll")                                                     \
        for (int s = 0; s < 2; ++s) {                                         \
            int chunk = s*2 + khalf;                                          \
            bf16x8 af0, af1, bfv;                                             \
            { int row = rA0;                                                  \
              u16x8 raw = *(const u16x8*)(sA + row*BK2 + 8*(chunk ^ ((row>>1)&3))); \
              af0 = __builtin_bit_cast(bf16x8, raw); }                        \
            { int row = rA0 + 32;                                             \
              u16x8 raw = *(const u16x8*)(sA + row*BK2 + 8*(chunk ^ ((row>>1)&3))); \
              af1 = __builtin_bit_cast(bf16x8, raw); }                        \
            { int row = rB0;                                                  \
              u16x8 raw = *(const u16x8*)(sB + row*BK2 + 8*(chunk ^ ((row>>1)&3))); \
              bfv = __builtin_bit_cast(bf16x8, raw); }                        \
            acc[0] = __builtin_amdgcn_mfma_f32_32x32x16_bf16(af0, bfv, acc[0], 0, 0, 0); \
            acc[1] = __builtin_amdgcn_mfma_f32_32x32x16_bf16(af1, bfv, acc[1], 0, 0, 0); \
        }                                                                     \
    }

    for (int kb = 0; kb < NITER; kb += 2) {
        // ---- stage 0: consume tile kb, refill with tile kb+2
        LDS_BARRIER();
        STORE_STAGE(a0, b0);
        LDS_BARRIER();
        if (kb + 2 < NITER) REFILL(a0, b0, (size_t)(kb+2)*BK2);
        MFMA_PHASE();
        // ---- stage 1: consume tile kb+1, refill with tile kb+3
        LDS_BARRIER();
        STORE_STAGE(a1, b1);
        LDS_BARRIER();
        if (kb + 3 < NITER) REFILL(a1, b1, (size_t)(kb+3)*BK2);
        MFMA_PHASE();
    }

    // bf16 partial C: C/D layout col=lane&31, row=(reg&3)+8*(reg>>2)+4*(lane>>5)
    u16* part = (u16*)(ws + PART_OFF_F) + ((size_t)blk << 14);
    #pragma unroll
    for (int mb = 0; mb < 2; ++mb) {
        int col = wn*32 + lrow;
        int rbase = wm*64 + mb*32 + 4*khalf;
        #pragma unroll
        for (int reg = 0; reg < 16; ++reg) {
            int row = rbase + (reg & 3) + 8*(reg >> 2);
            part[row*G_N + col] = f2bf(acc[mb][reg]);
        }
    }

    // per-chunk row stats, non-atomic (reduce over the 8 lanes sharing a row)
    #pragma unroll
    for (int i = 0; i < 2; ++i) {
        float sa = aS[i], qa = aQ[i], sb = bS[i], qb = bQ[i];
        #pragma unroll
        for (int m = 4; m >= 1; m >>= 1) {
            sa += __shfl_xor(sa, m, 64); qa += __shfl_xor(qa, m, 64);
            sb += __shfl_xor(sb, m, 64); qb += __shfl_xor(qb, m, 64);
        }
        if (c8 == 0) {
            int o = kch*2048 + b*G_N + (r0 + 64*i);
            if (half == 0) {
                ws[QSUM_P + o] = sa; ws[QSSQ_P + o] = qa;
                ws[KSUM_P + o] = sb; ws[KSSQ_P + o] = qb;
            } else {
                ws[NSSQ_P + o] = qb;
            }
        }
    }
}

// ================= K2: reduce chunks + normalize + write S / sm-row / CE-expsum-row ==========
// grid = 16b * 2half * 8rowgroups = 256 blocks x 256 thr. Also zeroes out[0] for K3's atomics.
__global__ __launch_bounds__(256)
void k_red2(float* __restrict__ ws, float* __restrict__ out)
{
    const int blk  = blockIdx.x;
    const int b    = blk >> 4;
    const int half = (blk >> 3) & 1;
    const int rg   = blk & 7;
    const int t    = threadIdx.x;
    const int lr   = t >> 4;            // 0..15
    const int i    = rg*16 + lr;
    const int c8   = t & 15;            // 8 cols each
    __shared__ float nrm[128];          // 1/||k_j|| or 1/||n_j||
    __shared__ float invq_s[16];

    if (blk == 0 && t == 0) out[0] = 0.f;

    if (t < 128) {
        float ss = 0.f;
        const float* p = ws + (half ? NSSQ_P : KSSQ_P) + b*G_N + t;
        #pragma unroll
        for (int kc2 = 0; kc2 < KSPLIT; ++kc2) ss += p[kc2*2048];
        nrm[t] = 1.f / fmaxf(sqrtf(ss), 1e-12f);
    } else if (t < 144) {
        float ss = 0.f;
        const float* p = ws + QSSQ_P + b*G_N + rg*16 + (t - 128);
        #pragma unroll
        for (int kc2 = 0; kc2 < KSPLIT; ++kc2) ss += p[kc2*2048];
        invq_s[t-128] = 1.f / fmaxf(sqrtf(ss), 1e-12f);
    }
    __syncthreads();

    const u16* part = (const u16*)(ws + PART_OFF_F);
    float s[8] = {0,0,0,0,0,0,0,0};
    #pragma unroll
    for (int kc2 = 0; kc2 < KSPLIT; ++kc2) {
        size_t idx = ((size_t)(b*32 + half*16 + kc2) << 14) + i*G_N + c8*8;
        u16x8 h = *(const u16x8*)(part + idx);
        #pragma unroll
        for (int e = 0; e < 8; ++e)
            s[e] += __uint_as_float(((uint32_t)h[e]) << 16);
    }
    const float iq = invq_s[lr];
    if (half == 0) {
        float smacc = 0.f;
        float S8[8];
        #pragma unroll
        for (int e = 0; e < 8; ++e) {
            int j = c8*8 + e;
            S8[e] = s[e] * iq * nrm[j];
            float d = S8[e] - (j == i ? 1.f : 0.f);
            smacc += d*d;
        }
        float* Sp = ws + S_OFF + (size_t)b*16384 + i*G_N + c8*8;
        float4 w0 = {S8[0],S8[1],S8[2],S8[3]};
        float4 w1 = {S8[4],S8[5],S8[6],S8[7]};
        *(float4*)Sp = w0; *(float4*)(Sp+4) = w1;
        #pragma unroll
        for (int m = 8; m >= 1; m >>= 1) smacc += __shfl_xor(smacc, m, 64);
        if (c8 == 0) ws[SM_ROW + b*G_N + i] = smacc;
    } else {
        float eacc = 0.f;
        #pragma unroll
        for (int e = 0; e < 8; ++e)
            eacc += __expf(5.f * s[e] * iq * nrm[c8*8+e]);
        #pragma unroll
        for (int m = 8; m >= 1; m >>= 1) eacc += __shfl_xor(eacc, m, 64);
        if (c8 == 0) ws[CE_ROW + b*G_N + i] = eacc;
    }
}

// ================= K3: tri/cyc/ce + weighted combine, atomic into out =================
// grid = 16b * 8rowgroups = 128 blocks x 256 thr. out[0] zeroed by K2 (stream-ordered).
__global__ __launch_bounds__(256)
void k_epi(float* __restrict__ ws, float* __restrict__ out)
{
    const int blk = blockIdx.x;
    const int b   = blk >> 3;
    const int i0  = (blk & 7) * 16;
    const int t   = threadIdx.x;
    __shared__ float sqv[128], skv[128], ddq[128], ddk[128];
    __shared__ float rbuf[4];
    const float c0 = (float)FD_N * 1e-6f * 1e-6f;

    const float* S = ws + S_OFF + (size_t)b * 16384;
    if (t < 128) {
        float qs=0, qq=0, ks=0, kq=0;
        #pragma unroll
        for (int kc2 = 0; kc2 < KSPLIT; ++kc2) {
            int o = kc2*2048 + b*G_N + t;
            qs += ws[QSUM_P + o]; qq += ws[QSSQ_P + o];
            ks += ws[KSUM_P + o]; kq += ws[KSSQ_P + o];
        }
        float iq = 1.f/fmaxf(sqrtf(qq),1e-12f);
        float ik = 1.f/fmaxf(sqrtf(kq),1e-12f);
        float sq = qs*iq, sk = ks*ik;
        sqv[t]=sq; skv[t]=sk;
        float Stt = S[t*G_N + t];
        ddq[t] = sqrtf(fmaxf(2.f - 2.f*Stt + 2e-6f*(sq-sk) + c0, 0.f));
        ddk[t] = sqrtf(fmaxf(2.f - 2.f*Stt + 2e-6f*(sk-sq) + c0, 0.f));
    }
    __syncthreads();

    float tri=0.f, cyc=0.f, ce=0.f, sm=0.f;
    #pragma unroll
    for (int p = 0; p < 8; ++p) {
        int idx = p*256 + t;
        int i = i0 + (idx >> 7), j = idx & 127;
        if (i != j) {
            float S_ij = S[i*G_N + j];
            float dqk = sqrtf(fmaxf(2.f - 2.f*S_ij + 2e-6f*(sqv[i]-skv[j]) + c0, 0.f));
            tri += fmaxf(ddq[i] - dqk + 1.f, 0.f);
            float dkq = sqrtf(fmaxf(2.f - 2.f*S_ij + 2e-6f*(skv[j]-sqv[i]) + c0, 0.f));
            tri += fmaxf(ddk[j] - dkq + 1.f, 0.f);
            cyc += fabsf(S_ij - S[j*G_N + i]);
        }
    }
    if (t < 16) {
        int r = i0 + t;
        float lp = 5.f * S[r*G_N + r];
        ce = __logf(ws[CE_ROW + b*G_N + r] + __expf(lp)) - lp;
        sm = ws[SM_ROW + b*G_N + r];
    }
    float contrib = sm * (1.f/16384.f) + cyc * (1.f/16256.f) + ce * (1.f/16384.f)
                  + (float)(B_N - b) * tri * (1.f/32512.f);
    #pragma unroll
    for (int m = 32; m >= 1; m >>= 1) contrib += __shfl_xor(contrib, m, 64);
    if ((t & 63) == 0) rbuf[t >> 6] = contrib;
    __syncthreads();
    if (t == 0) atomicAdd(out, rbuf[0] + rbuf[1] + rbuf[2] + rbuf[3]);
}

extern "C" void kernel_launch(void* const* d_in, const int* in_sizes, int n_in,
                              void* d_out, int out_size, void* d_ws, size_t ws_size,
                              hipStream_t stream)
{
    const float* q  = (const float*)d_in[0];
    const float* kM = (const float*)d_in[1];
    const float* nM = (const float*)d_in[2];
    float* ws  = (float*)d_ws;
    float* out = (float*)d_out;

    k_gemm<<<B_N * 2 * KSPLIT, 512, 0, stream>>>(q, kM, nM, ws);
    k_red2<<<256, 256, 0, stream>>>(ws, out);
    k_epi<<<128, 256, 0, stream>>>(ws, out);
}